// Round 11
// baseline (4648.520 us; speedup 1.0000x reference)
//
#include <hip/hip_runtime.h>
#include <hip/hip_fp16.h>

typedef unsigned int u32;
typedef unsigned long long u64;
typedef _Float16 half2_t __attribute__((ext_vector_type(2)));
typedef _Float16 f16x8 __attribute__((ext_vector_type(8)));
typedef float f32x16 __attribute__((ext_vector_type(16)));

static constexpr int PL = 300;
static constexpr int QL = 50;
static constexpr int B  = 32;
static constexpr int D  = 256;
static constexpr int H  = 256;

__device__ __forceinline__ float fdot2(u32 w, u32 x, float acc) {
    return __builtin_amdgcn_fdot2(__builtin_bit_cast(half2_t, w),
                                  __builtin_bit_cast(half2_t, x), acc, false);
}
__device__ __forceinline__ u32 packh2(float a, float b) {
    half2_t h2; h2[0] = (_Float16)a; h2[1] = (_Float16)b;
    return __builtin_bit_cast(u32, h2);
}
__device__ __forceinline__ f32x16 mfma16(uint4 a, uint4 b, f32x16 c) {
    return __builtin_amdgcn_mfma_f32_32x32x16_f16(
        __builtin_bit_cast(f16x8, a), __builtin_bit_cast(f16x8, b), c, 0, 0, 0);
}
__device__ __forceinline__ u32 a_ld32(const u32* p) {
    return __hip_atomic_load(p, __ATOMIC_RELAXED, __HIP_MEMORY_SCOPE_AGENT);
}
__device__ __forceinline__ u64 a_ld64(const u64* p) {
    return __hip_atomic_load(p, __ATOMIC_RELAXED, __HIP_MEMORY_SCOPE_AGENT);
}
__device__ __forceinline__ void a_st32(u32* p, u32 v) {
    __hip_atomic_store(p, v, __ATOMIC_RELAXED, __HIP_MEMORY_SCOPE_AGENT);
}
__device__ __forceinline__ void a_st64(u64* p, u64 v) {
    __hip_atomic_store(p, v, __ATOMIC_RELAXED, __HIP_MEMORY_SCOPE_AGENT);
}

// ---- pack MFMA weight tile per (dd,j): 32 rows = Whh gate rows (kind*256 + 8j + ci) ----
__global__ __launch_bounds__(256) void pack_wt3(const float* __restrict__ Whh,
                                                u32* __restrict__ dst) {
    int id = blockIdx.x * 256 + threadIdx.x;    // < 262144
    int u  = id & 127;
    int rw = (id >> 7) % 32;
    int j  = ((id >> 7) / 32) % 32;
    int dd = (id >> 7) / 1024;
    int R = (rw >> 3) * 256 + 8 * j + (rw & 7);
    float a = Whh[((size_t)dd * 1024 + R) * 256 + 2 * u];
    float c = Whh[((size_t)dd * 1024 + R) * 256 + 2 * u + 1];
    dst[id] = packh2(a, c);
}

// ---- pack Wr rows: Wrp[g][256 r][128 u] ----
__global__ __launch_bounds__(256) void pack_wr_rows(const float* __restrict__ W,
                                                    u32* __restrict__ dst) {
    int id = blockIdx.x * 256 + threadIdx.x;        // < 65536
    int g = id / 32768;
    int rem = id % 32768;
    int r = rem / 128, u = rem % 128;
    const float* s = &W[(g * 256 + r) * 256 + 2 * u];
    dst[id] = packh2(s[0], s[1]);
}

// ---- prep: out[g][b][t][h] = bias[g][h] + sum_d X[t][b][d]*W[g][h][d] ----
__global__ __launch_bounds__(256) void prep_proj(const float* __restrict__ X,
                                                 const float* __restrict__ W,
                                                 const float* __restrict__ Bv,
                                                 __half* __restrict__ out,
                                                 int T, int nt) {
    int id = blockIdx.x;
    int tb = id % nt; id /= nt;
    int b  = id % B;  id /= B;
    int g  = id;
    int t0 = tb * 8;
    int nr = T - t0; if (nr > 8) nr = 8;
    __shared__ __align__(16) float xs[8][256];
    int tid = threadIdx.x;
    for (int r = 0; r < nr; r++) xs[r][tid] = X[((t0 + r) * B + b) * D + tid];
    __syncthreads();
    const float4* wrow = (const float4*)&W[(g * H + tid) * D];
    float bb = Bv[g * H + tid];
    float acc[8];
#pragma unroll
    for (int r = 0; r < 8; r++) acc[r] = bb;
    for (int d4 = 0; d4 < D / 4; d4++) {
        float4 w = wrow[d4];
#pragma unroll
        for (int r = 0; r < 8; r++) {
            float4 x = *(const float4*)&xs[r][d4 * 4];
            acc[r] = fmaf(w.x, x.x, fmaf(w.y, x.y, fmaf(w.z, x.z, fmaf(w.w, x.w, acc[r]))));
        }
    }
    for (int r = 0; r < nr; r++)
        out[((g * B + b) * T + t0 + r) * H + tid] = __float2half(acc[r]);
}

// ---- P1[dd][b][t][1024] f16 = sum_{k<256} Wih[dd][R][k]*lng[dd][k]*cv[t][b][k] ----
__global__ __launch_bounds__(256) void p1_prep(const float* __restrict__ cv,
                                               const float* __restrict__ Wih,
                                               const float* __restrict__ lng,
                                               __half* __restrict__ P1) {
    int id = blockIdx.x;           // 2*32*38
    int tb = id % 38; id /= 38;
    int b  = id % 32; id /= 32;
    int dd = id;
    int t0 = tb * 8;
    int nr = PL - t0; if (nr > 8) nr = 8;
    __shared__ __align__(16) float xs[8][256];
    int tid = threadIdx.x;
    float g = lng[dd * 512 + tid];
    for (int r = 0; r < nr; r++)
        xs[r][tid] = cv[((size_t)(t0 + r) * B + b) * D + tid] * g;
    __syncthreads();
    for (int gc = 0; gc < 4; gc++) {
        int R = gc * 256 + tid;
        const float4* wrow = (const float4*)&Wih[((size_t)dd * 1024 + R) * 512];
        float acc[8] = {};
        for (int d4 = 0; d4 < 64; d4++) {
            float4 w = wrow[d4];
#pragma unroll
            for (int r = 0; r < 8; r++) {
                float4 x = *(const float4*)&xs[r][d4 * 4];
                acc[r] = fmaf(w.x, x.x, fmaf(w.y, x.y, fmaf(w.z, x.z, fmaf(w.w, x.w, acc[r]))));
            }
        }
        for (int r = 0; r < nr; r++)
            P1[((size_t)(dd * 32 + b) * PL + t0 + r) * 1024 + R] = __float2half(acc[r]);
    }
}

// ---- VP[dd][b][r][56 q] f16 = sum_k Wih[dd][r][256+k]*lng[dd][256+k]*qv[q][b][k] ----
__global__ __launch_bounds__(256) void vp_prep(const float* __restrict__ qv,
                                               const float* __restrict__ Wih,
                                               const float* __restrict__ lng,
                                               __half* __restrict__ VP) {
    int blk = blockIdx.x;               // 512
    int dd = blk >> 8, b = (blk >> 3) & 31, rc = blk & 7;
    __shared__ __align__(16) u32 qg[50 * 128];
    __shared__ __align__(16) u32 wch[128 * 128];
    int tid = threadIdx.x;
    for (int v = tid; v < 6400; v += 256) {
        int q = v >> 7, i = v & 127;
        float a = qv[((size_t)q * 32 + b) * 256 + 2 * i]     * lng[dd * 512 + 256 + 2 * i];
        float c = qv[((size_t)q * 32 + b) * 256 + 2 * i + 1] * lng[dd * 512 + 256 + 2 * i + 1];
        qg[v] = packh2(a, c);
    }
    for (int v = tid; v < 16384; v += 256) {
        int rl = v >> 7, i = v & 127;
        int r = rc * 128 + rl;
        float a = Wih[((size_t)dd * 1024 + r) * 512 + 256 + 2 * i];
        float c = Wih[((size_t)dd * 1024 + r) * 512 + 256 + 2 * i + 1];
        wch[v] = packh2(a, c);
    }
    __syncthreads();
    for (int p = tid; p < 128 * 56; p += 256) {
        int rl = p / 56, q = p % 56;
        int r = rc * 128 + rl;
        float acc = 0.f;
        if (q < 50) {
            const u32* qr = qg + q * 128;
            const u32* wr = wch + rl * 128;
#pragma unroll 8
            for (int i = 0; i < 128; i++) acc = fdot2(wr[i], qr[i], acc);
        }
        VP[((size_t)(dd * 32 + b) * 1024 + r) * 56 + q] = __float2half(acc);
    }
}

// ---- Gram G[b][50][50], rowsums qs[b][52] ----
__global__ __launch_bounds__(256) void gram_prep(const float* __restrict__ qv,
                                                 float* __restrict__ G,
                                                 float* __restrict__ qs) {
    int b = blockIdx.x;
    __shared__ float qvs[50 * 256];
    int tid = threadIdx.x;
    for (int v = tid; v < 12800; v += 256) {
        int q = v >> 8, k = v & 255;
        qvs[v] = qv[((size_t)q * 32 + b) * 256 + k];
    }
    __syncthreads();
    for (int p = tid; p < 2500; p += 256) {
        int q = p / 50, q2 = p % 50;
        float acc = 0.f;
        for (int k = 0; k < 256; k++) acc = fmaf(qvs[q * 256 + k], qvs[q2 * 256 + k], acc);
        G[((size_t)b * 50 + q) * 50 + q2] = acc;
    }
    if (tid < 52) {
        float s = 0.f;
        if (tid < 50) for (int k = 0; k < 256; k++) s += qvs[tid * 256 + k];
        qs[b * 52 + tid] = s;
    }
}

// ---- cvstats[b][t][2] = {sum, sumsq} over cv[t,b,:] ----
__global__ __launch_bounds__(256) void cvstats_prep(const float* __restrict__ cv,
                                                    float* __restrict__ st) {
    int blk = blockIdx.x;               // 9600
    int t = blk >> 5, b = blk & 31;
    int tid = threadIdx.x;
    float v = cv[((size_t)t * 32 + b) * 256 + tid];
    float s = v, s2 = v * v;
#pragma unroll
    for (int m = 32; m; m >>= 1) { s += __shfl_xor(s, m, 64); s2 += __shfl_xor(s2, m, 64); }
    __shared__ float red[8];
    if ((tid & 63) == 0) { red[(tid >> 6) * 2] = s; red[(tid >> 6) * 2 + 1] = s2; }
    __syncthreads();
    if (tid == 0) {
        float S = red[0] + red[2] + red[4] + red[6];
        float S2 = red[1] + red[3] + red[5] + red[7];
        st[((size_t)b * 300 + t) * 2] = S;
        st[((size_t)b * 300 + t) * 2 + 1] = S2;
    }
}

// ---- C12[dd][R][2] = {sum_k W[R,k]*gamma[k], sum_k W[R,k]*beta[k] + bih + bhh} ----
__global__ __launch_bounds__(256) void c1c2_prep(const float* __restrict__ Wih,
                                                 const float* __restrict__ lng,
                                                 const float* __restrict__ lnb,
                                                 const float* __restrict__ bih,
                                                 const float* __restrict__ bhh,
                                                 float* __restrict__ C12) {
    int id = blockIdx.x * 256 + threadIdx.x;    // < 2048
    int dd = id >> 10, R = id & 1023;
    float s1 = 0.f, s2 = 0.f;
    const float* wr = &Wih[((size_t)dd * 1024 + R) * 512];
    for (int k = 0; k < 512; k++) {
        float w = wr[k];
        s1 = fmaf(w, lng[dd * 512 + k], s1);
        s2 = fmaf(w, lnb[dd * 512 + k], s2);
    }
    C12[(size_t)id * 2] = s1;
    C12[(size_t)id * 2 + 1] = s2 + bih[dd * 1024 + R] + bhh[dd * 1024 + R];
}

// ================= main scan: 64 blocks; local hr; single B2 exchange + h exchange =================
__global__ __launch_bounds__(256, 1) void scan11(
    const int*   __restrict__ cmask,    // [32][300]
    const int*   __restrict__ qmask,    // [32][50]
    const float* __restrict__ Wgv,      // [2][256]
    const float* __restrict__ bgv,      // [2]
    const float* __restrict__ brp,      // [2][256]
    const u32*   __restrict__ Wtp,      // [2*32][32][128]
    const u32*   __restrict__ Wrp,      // [2][256][128]
    const __half* __restrict__ whp,     // [2][32][50][256]
    const __half* __restrict__ hpp,     // [2][32][300][256]
    const __half* __restrict__ P1,      // [2*32][300][1024]
    const __half* __restrict__ VP,      // [2*32][1024][56]
    const float* __restrict__ C12,      // [2][1024][2]
    const float* __restrict__ G,        // [32][50][50]
    const float* __restrict__ qsr,      // [32][52]
    const float* __restrict__ cvst,     // [32][300][2]
    u64* __restrict__ HX,               // [2*32][128]  seq32|2f16
    u32* __restrict__ B2X,              // [2*32][1024] f32&~511|seq9
    float* __restrict__ out)            // [300][32][512]
{
    int blk = blockIdx.x;
    int dd = blk >> 5, j = blk & 31;
    int tid = threadIdx.x;
    int lane = tid & 63, wave = tid >> 6;
    int rr = lane & 31, kh = lane >> 5, sw = rr & 7;

    __shared__ __align__(16) u32 sh_wt[32 * 128];
    __shared__ __align__(16) u32 sh_x[32 * 128];
    __shared__ __align__(16) u32 sh_wh[6400];
    __shared__ float sh_G[50 * 50];
    __shared__ float sh_red[4 * 32 * 33];
    __shared__ float sh_a[256];
    __shared__ float sh_af[64];
    __shared__ __align__(16) u32 sh_al2[28];
    __shared__ float sh_alpha[64];
    __shared__ float sh_qb[64];
    __shared__ float sh_qs[52];
    __shared__ float sh_r2[4];
    __shared__ float sh_cs[2];
    __shared__ int   sh_len[32];
    __shared__ __align__(16) u32 sh_hj[128];    // own-batch h(t) f16 pairs

    // ---------- one-time staging ----------
    for (int v = tid; v < 32 * 128; v += 256) {
        int rl = v >> 7, u = v & 127;
        int c4 = u >> 2, w = u & 3;
        sh_wt[rl * 128 + (((c4 ^ (rl & 7)) << 2) | w)] =
            Wtp[((size_t)(dd * 32 + j) * 32 + rl) * 128 + u];
    }
    {
        const u32* whsrc = (const u32*)(whp + (size_t)(dd * 32 + j) * QL * H);
        for (int i = tid; i < 6400; i += 256) sh_wh[i] = whsrc[i];
    }
    for (int v = tid; v < 2500; v += 256) sh_G[v] = G[(size_t)j * 2500 + v];
    if (tid < 52) sh_qs[tid] = qsr[j * 52 + tid];
    if (tid < 64) sh_qb[tid] = (tid < QL) ? (qmask[j * QL + tid] ? 0.f : -1e30f) : -1e30f;
    if (tid < 128) sh_hj[tid] = 0;
    if (tid < 32) sh_len[tid] = 0;
    __syncthreads();
    {
        int b = tid & 31, part = tid >> 5;
        int t0 = part * 38, t1 = t0 + 38 > PL ? PL : t0 + 38;
        int s = 0;
        for (int tt = t0; tt < t1; tt++) s += cmask[b * PL + tt];
        atomicAdd(&sh_len[b], s);
    }
    __syncthreads();

    float wgr[4];
#pragma unroll
    for (int i = 0; i < 4; i++) wgr[i] = Wgv[dd * H + lane + 64 * i];
    float bgs = bgv[dd];
    float brv = brp[dd * H + tid];
    float C1r[4], C2r[4];
#pragma unroll
    for (int k = 0; k < 4; k++) {
        C1r[k] = C12[((size_t)dd * 1024 + k * 256 + tid) * 2];
        C2r[k] = C12[((size_t)dd * 1024 + k * 256 + tid) * 2 + 1];
    }
    int len_j = sh_len[j];
    float c_reg = 0.f;

    // zero own-batch masked tail
    for (int t = len_j; t < PL; t++)
        out[((size_t)t * B + j) * 512 + dd * 256 + tid] = 0.f;

    // prologue: publish h(0)=0 with seq 1
    if (tid < 128) a_st64(HX + (size_t)(dd * 32 + j) * 128 + tid, ((u64)1 << 32));

    const __half* hpb = hpp + (size_t)(dd * 32 + j) * PL * H;
    const u32* VPu = (const u32*)VP;
    const uint4* wr4 = (const uint4*)(Wrp + ((size_t)dd * 256 + tid) * 128);
    const u32* xrow = sh_x + rr * 128;
    const u32* wrow = sh_wt + rr * 128;

    for (int t = 0; t < PL; t++) {
        u32 want = (u32)(t + 1);
        u32 want9 = want & 511;
        int tsj = dd ? (t < len_j ? len_j - 1 - t : t) : t;
        __syncthreads();   // step boundary: sh_hj/sh_a/sh_cs settle

        // ---- A: own-batch loads (L2/LLC cached, off critical path) ----
        float p1v[4];
#pragma unroll
        for (int k = 0; k < 4; k++)
            p1v[k] = __half2float(P1[((size_t)(dd * 32 + j) * PL + tsj) * 1024 + k * 256 + tid]);
        float hpv = __half2float(hpb[(size_t)tsj * H + tid]);
        if (tid == 0) {
            sh_cs[0] = cvst[((size_t)j * 300 + tsj) * 2];
            sh_cs[1] = cvst[((size_t)j * 300 + tsj) * 2 + 1];
        }

        // ---- X: local hr = Wr . h_j(t)  (Wr streamed from L2, h_j LDS-broadcast) ----
        {
            float p0 = 0.f, p1 = 0.f, p2 = 0.f, p3 = 0.f;
#pragma unroll 8
            for (int kk = 0; kk < 32; kk++) {
                uint4 w = wr4[kk];
                uint4 hx = *(const uint4*)(sh_hj + kk * 4);
                p0 = fdot2(w.x, hx.x, p0); p1 = fdot2(w.y, hx.y, p1);
                p2 = fdot2(w.z, hx.z, p2); p3 = fdot2(w.w, hx.w, p3);
            }
            sh_a[tid] = (p0 + p1) + (p2 + p3) + brv + hpv;
        }

        // ---- B: batched h poll (16 u64) + stage ----
        {
            const u64* base = HX + (size_t)dd * 32 * 128;
            u64 v[16];
            for (;;) {
                bool ok = true;
#pragma unroll
                for (int m = 0; m < 16; m++) v[m] = a_ld64(base + m * 256 + tid);
#pragma unroll
                for (int m = 0; m < 16; m++) ok &= ((u32)(v[m] >> 32) == want);
                if (ok) break;
                __builtin_amdgcn_s_sleep(2);
            }
#pragma unroll
            for (int m = 0; m < 16; m++) {
                int w = m * 256 + tid;
                int b = w >> 7, c2 = w & 127;
                sh_x[b * 128 + (((c2 >> 2) ^ (b & 7)) << 2) + (c2 & 3)] = (u32)v[m];
            }
        }
        __syncthreads();

        // ---- C: MFMA over h (K=256 split over 4 waves): gate rows ----
        {
            f32x16 acc1 = {};
#pragma unroll
            for (int kk = 0; kk < 4; kk++) {
                int c4 = wave * 8 + 2 * kk + kh;
                int pc4 = (c4 ^ sw) << 2;
                uint4 au = *(const uint4*)(xrow + pc4);
                uint4 b1 = *(const uint4*)(wrow + pc4);
                acc1 = mfma16(au, b1, acc1);
            }
#pragma unroll
            for (int q = 0; q < 16; q++) {
                int b = (q & 3) + 8 * (q >> 2) + 4 * kh;
                sh_red[(wave * 32 + b) * 33 + rr] = acc1[q];
            }
        }
        __syncthreads();

        // ---- D: reduce + publish B2 with seq9 in mantissa LSBs ----
        {
            int bb = tid >> 3, rq = (tid & 7) * 4;
            u32* dst = B2X + (size_t)(dd * 32 + bb) * 1024 + j * 32 + rq;
#pragma unroll
            for (int i = 0; i < 4; i++) {
                float f = sh_red[(0 * 32 + bb) * 33 + rq + i] + sh_red[(1 * 32 + bb) * 33 + rq + i]
                        + sh_red[(2 * 32 + bb) * 33 + rq + i] + sh_red[(3 * 32 + bb) * 33 + rq + i];
                a_st32(dst + i, (__builtin_bit_cast(u32, f) & ~511u) | want9);
            }
        }

        // ---- E: VP loads (own-batch alpha-VP weights, cached path) ----
        uint4 vp[28];
#pragma unroll
        for (int k = 0; k < 4; k++) {
            const uint4* vr = (const uint4*)(VPu + ((size_t)(dd * 32 + j) * 1024 + k * 256 + tid) * 28);
#pragma unroll
            for (int i = 0; i < 7; i++) vp[k * 7 + i] = vr[i];
        }

        // ---- G: attention logits (local; hides B2 transit) ----
        {
            float av[4];
#pragma unroll
            for (int i = 0; i < 4; i++) av[i] = sh_a[lane + 64 * i];
            const __half* wh16 = (const __half*)sh_wh;
            for (int q = wave; q < QL; q += 4) {
                float a = 0.f;
#pragma unroll
                for (int i = 0; i < 4; i++) {
                    float xx = (float)wh16[q * 256 + lane + 64 * i] + av[i];
                    float e = __expf(2.f * xx);
                    a = fmaf(wgr[i], (e - 1.f) / (e + 1.f), a);
                }
#pragma unroll
                for (int m = 32; m; m >>= 1) a += __shfl_xor(a, m, 64);
                if (lane == 0) sh_alpha[q] = a + bgs + sh_qb[q];
            }
        }
        __syncthreads();

        // ---- H: softmax (wave 0) ----
        if (wave == 0) {
            float v = (lane < QL) ? sh_alpha[lane] : -1e30f;
            float m = v;
#pragma unroll
            for (int s = 32; s; s >>= 1) m = fmaxf(m, __shfl_xor(m, s, 64));
            float e = (lane < QL) ? __expf(v - m) : 0.f;
            float sum = e;
#pragma unroll
            for (int s = 32; s; s >>= 1) sum += __shfl_xor(sum, s, 64);
            float al = (lane < QL) ? e / sum : 0.f;
            sh_af[lane] = al;
            float alo = __shfl_xor(al, 1, 64);
            if (!(lane & 1) && lane < 56) sh_al2[lane >> 1] = packh2(al, alo);
        }
        __syncthreads();

        // ---- I: LN stats from Gram ----
        if (wave == 0) {
            float gd = 0.f;
            if (lane < QL) {
                const float* Grow = sh_G + lane * 50;
                float aq = sh_af[lane];
                for (int q2 = 0; q2 < QL; q2++) gd = fmaf(Grow[q2], sh_af[q2], gd);
                gd *= aq;
            }
#pragma unroll
            for (int m = 32; m; m >>= 1) gd += __shfl_xor(gd, m, 64);
            if (lane == 0) sh_r2[0] = gd;
        } else if (wave == 1) {
            float s = (lane < QL) ? sh_af[lane] * sh_qs[lane] : 0.f;
#pragma unroll
            for (int m = 32; m; m >>= 1) s += __shfl_xor(s, m, 64);
            if (lane == 0) sh_r2[1] = s;
        }
        __syncthreads();

        // ---- J: alpha . VP ----
        float aVP[4];
#pragma unroll
        for (int k = 0; k < 4; k++) {
            float acc = 0.f;
#pragma unroll
            for (int i = 0; i < 7; i++) {
                acc = fdot2(vp[k * 7 + i].x, sh_al2[i * 4 + 0], acc);
                acc = fdot2(vp[k * 7 + i].y, sh_al2[i * 4 + 1], acc);
                acc = fdot2(vp[k * 7 + i].z, sh_al2[i * 4 + 2], acc);
                acc = fdot2(vp[k * 7 + i].w, sh_al2[i * 4 + 3], acc);
            }
            aVP[k] = acc;
        }

        // ---- F: batched B2 poll (4 independent words per retry) ----
        float bg2[4];
        {
            const u32* b2b = B2X + (size_t)(dd * 32 + j) * 1024 + (tid >> 3) * 32 + (tid & 7);
            u32 v0, v1, v2, v3;
            for (;;) {
                v0 = a_ld32(b2b);
                v1 = a_ld32(b2b + 8);
                v2 = a_ld32(b2b + 16);
                v3 = a_ld32(b2b + 24);
                bool ok = ((v0 & 511) == want9) & ((v1 & 511) == want9)
                        & ((v2 & 511) == want9) & ((v3 & 511) == want9);
                if (ok) break;
                __builtin_amdgcn_s_sleep(2);
            }
            bg2[0] = __builtin_bit_cast(float, v0 & ~511u);
            bg2[1] = __builtin_bit_cast(float, v1 & ~511u);
            bg2[2] = __builtin_bit_cast(float, v2 & ~511u);
            bg2[3] = __builtin_bit_cast(float, v3 & ~511u);
        }

        // ---- K: gates + LSTM pointwise + publish h(t+1) ----
        float hv;
        {
            float mu = (sh_cs[0] + sh_r2[1]) * (1.f / 512.f);
            float E2 = (sh_cs[1] + sh_r2[0]) * (1.f / 512.f);
            float rs = rsqrtf(E2 - mu * mu + 1e-5f);
            float gk[4];
#pragma unroll
            for (int k = 0; k < 4; k++)
                gk[k] = rs * (p1v[k] + aVP[k]) - rs * mu * C1r[k] + C2r[k] + bg2[k];
            float si = 1.f / (1.f + __expf(-gk[0]));
            float sf = 1.f / (1.f + __expf(-gk[1]));
            float so = 1.f / (1.f + __expf(-gk[3]));
            float eg = __expf(2.f * gk[2]); float tg = (eg - 1.f) / (eg + 1.f);
            float c = sf * c_reg + si * tg;
            float ec = __expf(2.f * c); float tc = (ec - 1.f) / (ec + 1.f);
            hv = so * tc;
            c_reg = c;
            float ho = __shfl_xor(hv, 1, 64);
            if (!(tid & 1)) {
                u32 pk = packh2(hv, ho);
                sh_hj[tid >> 1] = pk;
                a_st64(HX + (size_t)(dd * 32 + j) * 128 + (tid >> 1),
                       (((u64)(t + 2)) << 32) | (u64)pk);
            }
        }

        // ---- L: output store ----
        if (t < len_j)
            out[((size_t)tsj * B + j) * 512 + dd * 256 + tid] = hv;
    }
}

extern "C" void kernel_launch(void* const* d_in, const int* in_sizes, int n_in,
                              void* d_out, int out_size, void* d_ws, size_t ws_size,
                              hipStream_t stream) {
    const float* cv    = (const float*)d_in[0];
    const int*   cmask = (const int*)  d_in[1];
    const float* qv    = (const float*)d_in[2];
    const int*   qmask = (const int*)  d_in[3];
    const float* Wq    = (const float*)d_in[4];
    const float* bq    = (const float*)d_in[5];
    const float* Wp    = (const float*)d_in[6];
    const float* bp    = (const float*)d_in[7];
    const float* Wr    = (const float*)d_in[8];
    const float* br    = (const float*)d_in[9];
    const float* Wg    = (const float*)d_in[10];
    const float* bg    = (const float*)d_in[11];
    const float* ln_g  = (const float*)d_in[12];
    const float* ln_b  = (const float*)d_in[13];
    const float* Wih   = (const float*)d_in[14];
    const float* Whh   = (const float*)d_in[15];
    const float* b_ih  = (const float*)d_in[16];
    const float* b_hh  = (const float*)d_in[17];
    float* out = (float*)d_out;

    uint8_t* ws = (uint8_t*)d_ws;
    u32*    Wtp = (u32*)ws;      ws += (size_t)2 * 32 * 32 * 128 * 4;   // 1.05 MB
    u32*    Wrp = (u32*)ws;      ws += (size_t)2 * 256 * 128 * 4;       // 256 KB
    __half* VP  = (__half*)ws;   ws += (size_t)2 * 32 * 1024 * 56 * 2;  // 7.34 MB
    __half* whp = (__half*)ws;   ws += (size_t)2 * 32 * 50 * 256 * 2;   // 1.64 MB
    __half* hpp = (__half*)ws;   ws += (size_t)2 * 32 * 300 * 256 * 2;  // 9.83 MB
    __half* P1  = (__half*)ws;   ws += (size_t)2 * 32 * 300 * 1024 * 2; // 39.32 MB
    float*  C12 = (float*)ws;    ws += (size_t)2 * 1024 * 2 * 4;        // 16 KB
    float*  G   = (float*)ws;    ws += (size_t)32 * 50 * 50 * 4;        // 320 KB
    float*  qs  = (float*)ws;    ws += (size_t)32 * 52 * 4;             // 6.7 KB
    float*  cvs = (float*)ws;    ws += (size_t)32 * 300 * 2 * 4;        // 77 KB
    u64* HX  = (u64*)ws;         ws += (size_t)2 * 32 * 128 * 8;        // 64 KB
    u32* B2X = (u32*)ws;         ws += (size_t)2 * 32 * 1024 * 4;       // 256 KB

    hipMemsetAsync(HX, 0, (size_t)2 * 32 * 128 * 8 + (size_t)2 * 32 * 1024 * 4, stream);
    hipLaunchKernelGGL(pack_wt3, dim3(1024), dim3(256), 0, stream, Whh, Wtp);
    hipLaunchKernelGGL(pack_wr_rows, dim3(256), dim3(256), 0, stream, Wr, Wrp);
    hipLaunchKernelGGL(prep_proj, dim3(2 * 32 * 7), dim3(256), 0, stream,
                       qv, Wq, bq, whp, QL, 7);
    hipLaunchKernelGGL(prep_proj, dim3(2 * 32 * 38), dim3(256), 0, stream,
                       cv, Wp, bp, hpp, PL, 38);
    hipLaunchKernelGGL(p1_prep, dim3(2 * 32 * 38), dim3(256), 0, stream,
                       cv, Wih, ln_g, P1);
    hipLaunchKernelGGL(vp_prep, dim3(512), dim3(256), 0, stream, qv, Wih, ln_g, VP);
    hipLaunchKernelGGL(gram_prep, dim3(32), dim3(256), 0, stream, qv, G, qs);
    hipLaunchKernelGGL(cvstats_prep, dim3(9600), dim3(256), 0, stream, cv, cvs);
    hipLaunchKernelGGL(c1c2_prep, dim3(8), dim3(256), 0, stream,
                       Wih, ln_g, ln_b, b_ih, b_hh, C12);
    hipLaunchKernelGGL(scan11, dim3(64), dim3(256), 0, stream,
                       cmask, qmask, Wg, bg, br, Wtp, Wrp, whp, hpp, P1, VP, C12, G, qs, cvs,
                       HX, B2X, out);
}

// Round 12
// 4639.557 us; speedup vs baseline: 1.0019x; 1.0019x over previous
//
#include <hip/hip_runtime.h>
#include <hip/hip_fp16.h>

typedef unsigned int u32;
typedef unsigned long long u64;
typedef _Float16 half2_t __attribute__((ext_vector_type(2)));

static constexpr int PL = 300;
static constexpr int QL = 50;
static constexpr int B  = 32;
static constexpr int D  = 256;
static constexpr int H  = 256;

__device__ __forceinline__ float fdot2(u32 w, u32 x, float acc) {
    return __builtin_amdgcn_fdot2(__builtin_bit_cast(half2_t, w),
                                  __builtin_bit_cast(half2_t, x), acc, false);
}
__device__ __forceinline__ u32 packh2(float a, float b) {
    half2_t h2; h2[0] = (_Float16)a; h2[1] = (_Float16)b;
    return __builtin_bit_cast(u32, h2);
}

// ---- pack Whh chunk8: dst[((dd*32+kc)*1024 + R)*4 + w] = cols kc*8+2w,+1 of row R ----
__global__ __launch_bounds__(256) void pack_whh(const float* __restrict__ Whh,
                                                u32* __restrict__ dst) {
    int id = blockIdx.x * 256 + threadIdx.x;    // < 262144
    int dd = id >> 17;
    int r  = id & 131071;
    int kc = r >> 12;
    int R  = (r >> 2) & 1023;
    int w  = r & 3;
    int k  = kc * 8 + w * 2;
    const float* s = &Whh[((size_t)dd * 1024 + R) * 256 + k];
    dst[id] = packh2(s[0], s[1]);
}

// ---- pack Wr chunk8: dst[((g*32+kc)*256 + c)*4 + w] ----
__global__ __launch_bounds__(256) void pack_wr8(const float* __restrict__ W,
                                                u32* __restrict__ dst) {
    int id = blockIdx.x * 256 + threadIdx.x;    // < 65536
    int g  = id >> 15;
    int r  = id & 32767;
    int kc = r >> 10;
    int c  = (r >> 2) & 255;
    int w  = r & 3;
    int k  = kc * 8 + w * 2;
    const float* s = &W[(g * 256 + c) * 256 + k];
    dst[id] = packh2(s[0], s[1]);
}

// ---- prep: out[g][b][t][h] = bias[g][h] + sum_d X[t][b][d]*W[g][h][d] ----
__global__ __launch_bounds__(256) void prep_proj(const float* __restrict__ X,
                                                 const float* __restrict__ W,
                                                 const float* __restrict__ Bv,
                                                 __half* __restrict__ out,
                                                 int T, int nt) {
    int id = blockIdx.x;
    int tb = id % nt; id /= nt;
    int b  = id % B;  id /= B;
    int g  = id;
    int t0 = tb * 8;
    int nr = T - t0; if (nr > 8) nr = 8;
    __shared__ __align__(16) float xs[8][256];
    int tid = threadIdx.x;
    for (int r = 0; r < nr; r++) xs[r][tid] = X[((t0 + r) * B + b) * D + tid];
    __syncthreads();
    const float4* wrow = (const float4*)&W[(g * H + tid) * D];
    float bb = Bv[g * H + tid];
    float acc[8];
#pragma unroll
    for (int r = 0; r < 8; r++) acc[r] = bb;
    for (int d4 = 0; d4 < D / 4; d4++) {
        float4 w = wrow[d4];
#pragma unroll
        for (int r = 0; r < 8; r++) {
            float4 x = *(const float4*)&xs[r][d4 * 4];
            acc[r] = fmaf(w.x, x.x, fmaf(w.y, x.y, fmaf(w.z, x.z, fmaf(w.w, x.w, acc[r]))));
        }
    }
    for (int r = 0; r < nr; r++)
        out[((g * B + b) * T + t0 + r) * H + tid] = __float2half(acc[r]);
}

// ---- P1[dd][b][t][1024] f16 = sum_{k<256} Wih[dd][R][k]*lng[dd][k]*cv[t][b][k] ----
__global__ __launch_bounds__(256) void p1_prep(const float* __restrict__ cv,
                                               const float* __restrict__ Wih,
                                               const float* __restrict__ lng,
                                               __half* __restrict__ P1) {
    int id = blockIdx.x;           // 2*32*38
    int tb = id % 38; id /= 38;
    int b  = id % 32; id /= 32;
    int dd = id;
    int t0 = tb * 8;
    int nr = PL - t0; if (nr > 8) nr = 8;
    __shared__ __align__(16) float xs[8][256];
    int tid = threadIdx.x;
    float g = lng[dd * 512 + tid];
    for (int r = 0; r < nr; r++)
        xs[r][tid] = cv[((size_t)(t0 + r) * B + b) * D + tid] * g;
    __syncthreads();
    for (int gc = 0; gc < 4; gc++) {
        int R = gc * 256 + tid;
        const float4* wrow = (const float4*)&Wih[((size_t)dd * 1024 + R) * 512];
        float acc[8] = {};
        for (int d4 = 0; d4 < 64; d4++) {
            float4 w = wrow[d4];
#pragma unroll
            for (int r = 0; r < 8; r++) {
                float4 x = *(const float4*)&xs[r][d4 * 4];
                acc[r] = fmaf(w.x, x.x, fmaf(w.y, x.y, fmaf(w.z, x.z, fmaf(w.w, x.w, acc[r]))));
            }
        }
        for (int r = 0; r < nr; r++)
            P1[((size_t)(dd * 32 + b) * PL + t0 + r) * 1024 + R] = __float2half(acc[r]);
    }
}

// ---- VP[dd][b][r][56 q] f16 = sum_k Wih[dd][r][256+k]*lng[dd][256+k]*qv[q][b][k] ----
__global__ __launch_bounds__(256) void vp_prep(const float* __restrict__ qv,
                                               const float* __restrict__ Wih,
                                               const float* __restrict__ lng,
                                               __half* __restrict__ VP) {
    int blk = blockIdx.x;               // 512
    int dd = blk >> 8, b = (blk >> 3) & 31, rc = blk & 7;
    __shared__ __align__(16) u32 qg[50 * 128];
    __shared__ __align__(16) u32 wch[128 * 128];
    int tid = threadIdx.x;
    for (int v = tid; v < 6400; v += 256) {
        int q = v >> 7, i = v & 127;
        float a = qv[((size_t)q * 32 + b) * 256 + 2 * i]     * lng[dd * 512 + 256 + 2 * i];
        float c = qv[((size_t)q * 32 + b) * 256 + 2 * i + 1] * lng[dd * 512 + 256 + 2 * i + 1];
        qg[v] = packh2(a, c);
    }
    for (int v = tid; v < 16384; v += 256) {
        int rl = v >> 7, i = v & 127;
        int r = rc * 128 + rl;
        float a = Wih[((size_t)dd * 1024 + r) * 512 + 256 + 2 * i];
        float c = Wih[((size_t)dd * 1024 + r) * 512 + 256 + 2 * i + 1];
        wch[v] = packh2(a, c);
    }
    __syncthreads();
    for (int p = tid; p < 128 * 56; p += 256) {
        int rl = p / 56, q = p % 56;
        int r = rc * 128 + rl;
        float acc = 0.f;
        if (q < 50) {
            const u32* qr = qg + q * 128;
            const u32* wr = wch + rl * 128;
#pragma unroll 8
            for (int i = 0; i < 128; i++) acc = fdot2(wr[i], qr[i], acc);
        }
        VP[((size_t)(dd * 32 + b) * 1024 + r) * 56 + q] = __float2half(acc);
    }
}

// ---- Gram G[b][50][50], rowsums qs[b][52] ----
__global__ __launch_bounds__(256) void gram_prep(const float* __restrict__ qv,
                                                 float* __restrict__ G,
                                                 float* __restrict__ qs) {
    int b = blockIdx.x;
    __shared__ float qvs[50 * 256];
    int tid = threadIdx.x;
    for (int v = tid; v < 12800; v += 256) {
        int q = v >> 8, k = v & 255;
        qvs[v] = qv[((size_t)q * 32 + b) * 256 + k];
    }
    __syncthreads();
    for (int p = tid; p < 2500; p += 256) {
        int q = p / 50, q2 = p % 50;
        float acc = 0.f;
        for (int k = 0; k < 256; k++) acc = fmaf(qvs[q * 256 + k], qvs[q2 * 256 + k], acc);
        G[((size_t)b * 50 + q) * 50 + q2] = acc;
    }
    if (tid < 52) {
        float s = 0.f;
        if (tid < 50) for (int k = 0; k < 256; k++) s += qvs[tid * 256 + k];
        qs[b * 52 + tid] = s;
    }
}

// ---- cvstats[b][t][2] = {sum, sumsq} over cv[t,b,:] ----
__global__ __launch_bounds__(256) void cvstats_prep(const float* __restrict__ cv,
                                                    float* __restrict__ st) {
    int blk = blockIdx.x;               // 9600
    int t = blk >> 5, b = blk & 31;
    int tid = threadIdx.x;
    float v = cv[((size_t)t * 32 + b) * 256 + tid];
    float s = v, s2 = v * v;
#pragma unroll
    for (int m = 32; m; m >>= 1) { s += __shfl_xor(s, m, 64); s2 += __shfl_xor(s2, m, 64); }
    __shared__ float red[8];
    if ((tid & 63) == 0) { red[(tid >> 6) * 2] = s; red[(tid >> 6) * 2 + 1] = s2; }
    __syncthreads();
    if (tid == 0) {
        float S = red[0] + red[2] + red[4] + red[6];
        float S2 = red[1] + red[3] + red[5] + red[7];
        st[((size_t)b * 300 + t) * 2] = S;
        st[((size_t)b * 300 + t) * 2 + 1] = S2;
    }
}

// ---- C12[dd][R][2] = {sum_k W[R,k]*gamma[k], sum_k W[R,k]*beta[k] + bih + bhh} ----
__global__ __launch_bounds__(256) void c1c2_prep(const float* __restrict__ Wih,
                                                 const float* __restrict__ lng,
                                                 const float* __restrict__ lnb,
                                                 const float* __restrict__ bih,
                                                 const float* __restrict__ bhh,
                                                 float* __restrict__ C12) {
    int id = blockIdx.x * 256 + threadIdx.x;    // < 2048
    int dd = id >> 10, R = id & 1023;
    float s1 = 0.f, s2 = 0.f;
    const float* wr = &Wih[((size_t)dd * 1024 + R) * 512];
    for (int k = 0; k < 512; k++) {
        float w = wr[k];
        s1 = fmaf(w, lng[dd * 512 + k], s1);
        s2 = fmaf(w, lnb[dd * 512 + k], s2);
    }
    C12[(size_t)id * 2] = s1;
    C12[(size_t)id * 2 + 1] = s2 + bih[dd * 1024 + R] + bhh[dd * 1024 + R];
}

// ================= main scan: 64 INDEPENDENT blocks (dir, batch); zero inter-block sync =================
// Per step: stream Whh (512 KB) + Wr (128 KB) from L2 against own h (LDS broadcast);
// all attention / LN algebra local (P1, VP, Gram, C12 precomputed).
__global__ __launch_bounds__(256, 1) void scan12(
    const int*   __restrict__ cmask,    // [32][300]
    const int*   __restrict__ qmask,    // [32][50]
    const float* __restrict__ Wgv,      // [2][256]
    const float* __restrict__ bgv,      // [2]
    const float* __restrict__ brp,      // [2][256]
    const u32*   __restrict__ WhhP,     // [2][32 kc][1024][4] chunk8
    const u32*   __restrict__ WrP,      // [2][32 kc][256][4] chunk8
    const __half* __restrict__ whp,     // [2][32][50][256]
    const __half* __restrict__ hpp,     // [2][32][300][256]
    const __half* __restrict__ P1,      // [2*32][300][1024]
    const __half* __restrict__ VP,      // [2*32][1024][56]
    const float* __restrict__ C12,      // [2][1024][2]
    const float* __restrict__ G,        // [32][50][50]
    const float* __restrict__ qsr,      // [32][52]
    const float* __restrict__ cvst,     // [32][300][2]
    float* __restrict__ out)            // [300][32][512]
{
    int blk = blockIdx.x;
    int dd = blk >> 5, j = blk & 31;
    int tid = threadIdx.x;
    int lane = tid & 63, wave = tid >> 6;

    __shared__ __align__(16) u32 sh_wh[6400];   // wh f16 [50][256]
    __shared__ float sh_G[50 * 50];
    __shared__ __align__(16) u32 sh_h[128];     // own h(t) f16 pairs
    __shared__ float sh_a[256];
    __shared__ float sh_af[64];
    __shared__ __align__(16) u32 sh_al2[28];
    __shared__ float sh_alpha[64];
    __shared__ float sh_qb[64];
    __shared__ float sh_qs[52];
    __shared__ float sh_r2[4];
    __shared__ float sh_cs[2];
    __shared__ int   sh_len1;

    // ---------- one-time staging ----------
    {
        const u32* whsrc = (const u32*)(whp + (size_t)(dd * 32 + j) * QL * H);
        for (int i = tid; i < 6400; i += 256) sh_wh[i] = whsrc[i];
    }
    for (int v = tid; v < 2500; v += 256) sh_G[v] = G[(size_t)j * 2500 + v];
    if (tid < 52) sh_qs[tid] = qsr[j * 52 + tid];
    if (tid < 64) sh_qb[tid] = (tid < QL) ? (qmask[j * QL + tid] ? 0.f : -1e30f) : -1e30f;
    if (tid < 128) sh_h[tid] = 0;
    if (tid == 0) sh_len1 = 0;
    __syncthreads();
    {
        int s = 0;
        for (int tt = tid; tt < PL; tt += 256) s += cmask[j * PL + tt];
#pragma unroll
        for (int m = 32; m; m >>= 1) s += __shfl_xor(s, m, 64);
        if (lane == 0) atomicAdd(&sh_len1, s);
    }
    __syncthreads();
    int len_j = sh_len1;

    float wgr[4];
#pragma unroll
    for (int i = 0; i < 4; i++) wgr[i] = Wgv[dd * H + lane + 64 * i];
    float bgs = bgv[dd];
    float brv = brp[dd * H + tid];
    float C1r[4], C2r[4];
#pragma unroll
    for (int k = 0; k < 4; k++) {
        C1r[k] = C12[((size_t)dd * 1024 + k * 256 + tid) * 2];
        C2r[k] = C12[((size_t)dd * 1024 + k * 256 + tid) * 2 + 1];
    }
    float c_reg = 0.f;

    // zero own-batch masked tail
    for (int t = len_j; t < PL; t++)
        out[((size_t)t * B + j) * 512 + dd * 256 + tid] = 0.f;

    const __half* hpb = hpp + (size_t)(dd * 32 + j) * PL * H;
    const u32* VPu = (const u32*)VP;
    const uint4* whq = (const uint4*)WhhP + (size_t)dd * 32 * 1024;  // [kc*1024 + R]
    const uint4* wrq = (const uint4*)WrP  + (size_t)dd * 32 * 256;   // [kc*256 + c]

    for (int t = 0; t < len_j; t++) {
        int tsj = dd ? (len_j - 1 - t) : t;
        __syncthreads();   // sh_h / sh_cs stable

        // ---- A: own-batch cached loads ----
        float p1v[4];
#pragma unroll
        for (int k = 0; k < 4; k++)
            p1v[k] = __half2float(P1[((size_t)(dd * 32 + j) * PL + tsj) * 1024 + k * 256 + tid]);
        float hpv = __half2float(hpb[(size_t)tsj * H + tid]);
        if (tid == 0) {
            sh_cs[0] = cvst[((size_t)j * 300 + tsj) * 2];
            sh_cs[1] = cvst[((size_t)j * 300 + tsj) * 2 + 1];
        }

        // ---- B: L2-streamed GEMV: gates-h part (4 rows) + hr (1 row) per thread ----
        float g0 = 0.f, g1 = 0.f, g2 = 0.f, g3 = 0.f, hr = 0.f;
#pragma unroll 4
        for (int kc = 0; kc < 32; kc++) {
            uint4 hx = *(const uint4*)(sh_h + kc * 4);          // LDS broadcast
            uint4 wa = whq[kc * 1024 + tid];
            uint4 wb = whq[kc * 1024 + 256 + tid];
            uint4 wc = whq[kc * 1024 + 512 + tid];
            uint4 wd = whq[kc * 1024 + 768 + tid];
            uint4 wr = wrq[kc * 256 + tid];
            g0 = fdot2(wa.x, hx.x, g0); g0 = fdot2(wa.y, hx.y, g0);
            g0 = fdot2(wa.z, hx.z, g0); g0 = fdot2(wa.w, hx.w, g0);
            g1 = fdot2(wb.x, hx.x, g1); g1 = fdot2(wb.y, hx.y, g1);
            g1 = fdot2(wb.z, hx.z, g1); g1 = fdot2(wb.w, hx.w, g1);
            g2 = fdot2(wc.x, hx.x, g2); g2 = fdot2(wc.y, hx.y, g2);
            g2 = fdot2(wc.z, hx.z, g2); g2 = fdot2(wc.w, hx.w, g2);
            g3 = fdot2(wd.x, hx.x, g3); g3 = fdot2(wd.y, hx.y, g3);
            g3 = fdot2(wd.z, hx.z, g3); g3 = fdot2(wd.w, hx.w, g3);
            hr = fdot2(wr.x, hx.x, hr); hr = fdot2(wr.y, hx.y, hr);
            hr = fdot2(wr.z, hx.z, hr); hr = fdot2(wr.w, hx.w, hr);
        }
        sh_a[tid] = hr + brv + hpv;

        // ---- E: prefetch VP rows (overlaps attention) ----
        uint4 vp[28];
#pragma unroll
        for (int k = 0; k < 4; k++) {
            const uint4* vr = (const uint4*)(VPu + ((size_t)(dd * 32 + j) * 1024 + k * 256 + tid) * 28);
#pragma unroll
            for (int i = 0; i < 7; i++) vp[k * 7 + i] = vr[i];
        }
        __syncthreads();

        // ---- G: attention logits ----
        {
            float av[4];
#pragma unroll
            for (int i = 0; i < 4; i++) av[i] = sh_a[lane + 64 * i];
            const __half* wh16 = (const __half*)sh_wh;
            for (int q = wave; q < QL; q += 4) {
                float a = 0.f;
#pragma unroll
                for (int i = 0; i < 4; i++) {
                    float xx = (float)wh16[q * 256 + lane + 64 * i] + av[i];
                    float e = __expf(2.f * xx);
                    a = fmaf(wgr[i], (e - 1.f) / (e + 1.f), a);
                }
#pragma unroll
                for (int m = 32; m; m >>= 1) a += __shfl_xor(a, m, 64);
                if (lane == 0) sh_alpha[q] = a + bgs + sh_qb[q];
            }
        }
        __syncthreads();

        // ---- H: softmax (wave 0) ----
        if (wave == 0) {
            float v = (lane < QL) ? sh_alpha[lane] : -1e30f;
            float m = v;
#pragma unroll
            for (int s = 32; s; s >>= 1) m = fmaxf(m, __shfl_xor(m, s, 64));
            float e = (lane < QL) ? __expf(v - m) : 0.f;
            float sum = e;
#pragma unroll
            for (int s = 32; s; s >>= 1) sum += __shfl_xor(sum, s, 64);
            float al = (lane < QL) ? e / sum : 0.f;
            sh_af[lane] = al;
            float alo = __shfl_xor(al, 1, 64);
            if (!(lane & 1) && lane < 56) sh_al2[lane >> 1] = packh2(al, alo);
        }
        __syncthreads();

        // ---- I: LN stats from Gram ----
        if (wave == 0) {
            float gd = 0.f;
            if (lane < QL) {
                const float* Grow = sh_G + lane * 50;
                float aq = sh_af[lane];
                for (int q2 = 0; q2 < QL; q2++) gd = fmaf(Grow[q2], sh_af[q2], gd);
                gd *= aq;
            }
#pragma unroll
            for (int m = 32; m; m >>= 1) gd += __shfl_xor(gd, m, 64);
            if (lane == 0) sh_r2[0] = gd;
        } else if (wave == 1) {
            float s = (lane < QL) ? sh_af[lane] * sh_qs[lane] : 0.f;
#pragma unroll
            for (int m = 32; m; m >>= 1) s += __shfl_xor(s, m, 64);
            if (lane == 0) sh_r2[1] = s;
        }
        __syncthreads();

        // ---- J: alpha . VP ----
        float aVP[4];
#pragma unroll
        for (int k = 0; k < 4; k++) {
            float acc = 0.f;
#pragma unroll
            for (int i = 0; i < 7; i++) {
                acc = fdot2(vp[k * 7 + i].x, sh_al2[i * 4 + 0], acc);
                acc = fdot2(vp[k * 7 + i].y, sh_al2[i * 4 + 1], acc);
                acc = fdot2(vp[k * 7 + i].z, sh_al2[i * 4 + 2], acc);
                acc = fdot2(vp[k * 7 + i].w, sh_al2[i * 4 + 3], acc);
            }
            aVP[k] = acc;
        }

        // ---- K: gates + LSTM pointwise + h(t+1) to LDS ----
        float hv;
        {
            float mu = (sh_cs[0] + sh_r2[1]) * (1.f / 512.f);
            float E2 = (sh_cs[1] + sh_r2[0]) * (1.f / 512.f);
            float rs = rsqrtf(E2 - mu * mu + 1e-5f);
            float gk[4] = { g0, g1, g2, g3 };
#pragma unroll
            for (int k = 0; k < 4; k++)
                gk[k] += rs * (p1v[k] + aVP[k]) - rs * mu * C1r[k] + C2r[k];
            float si = 1.f / (1.f + __expf(-gk[0]));
            float sf = 1.f / (1.f + __expf(-gk[1]));
            float so = 1.f / (1.f + __expf(-gk[3]));
            float eg = __expf(2.f * gk[2]); float tg = (eg - 1.f) / (eg + 1.f);
            float c = sf * c_reg + si * tg;
            float ec = __expf(2.f * c); float tc = (ec - 1.f) / (ec + 1.f);
            hv = so * tc;
            c_reg = c;
            float ho = __shfl_xor(hv, 1, 64);
            if (!(tid & 1)) sh_h[tid >> 1] = packh2(hv, ho);
        }

        // ---- L: output store ----
        out[((size_t)tsj * B + j) * 512 + dd * 256 + tid] = hv;
    }
}

extern "C" void kernel_launch(void* const* d_in, const int* in_sizes, int n_in,
                              void* d_out, int out_size, void* d_ws, size_t ws_size,
                              hipStream_t stream) {
    const float* cv    = (const float*)d_in[0];
    const int*   cmask = (const int*)  d_in[1];
    const float* qv    = (const float*)d_in[2];
    const int*   qmask = (const int*)  d_in[3];
    const float* Wq    = (const float*)d_in[4];
    const float* bq    = (const float*)d_in[5];
    const float* Wp    = (const float*)d_in[6];
    const float* bp    = (const float*)d_in[7];
    const float* Wr    = (const float*)d_in[8];
    const float* br    = (const float*)d_in[9];
    const float* Wg    = (const float*)d_in[10];
    const float* bg    = (const float*)d_in[11];
    const float* ln_g  = (const float*)d_in[12];
    const float* ln_b  = (const float*)d_in[13];
    const float* Wih   = (const float*)d_in[14];
    const float* Whh   = (const float*)d_in[15];
    const float* b_ih  = (const float*)d_in[16];
    const float* b_hh  = (const float*)d_in[17];
    float* out = (float*)d_out;

    uint8_t* ws = (uint8_t*)d_ws;
    u32*    WhhP = (u32*)ws;     ws += (size_t)2 * 32 * 1024 * 4 * 4;   // 1.05 MB
    u32*    WrP  = (u32*)ws;     ws += (size_t)2 * 32 * 256 * 4 * 4;    // 256 KB
    __half* VP  = (__half*)ws;   ws += (size_t)2 * 32 * 1024 * 56 * 2;  // 7.34 MB
    __half* whp = (__half*)ws;   ws += (size_t)2 * 32 * 50 * 256 * 2;   // 1.64 MB
    __half* hpp = (__half*)ws;   ws += (size_t)2 * 32 * 300 * 256 * 2;  // 9.83 MB
    __half* P1  = (__half*)ws;   ws += (size_t)2 * 32 * 300 * 1024 * 2; // 39.32 MB
    float*  C12 = (float*)ws;    ws += (size_t)2 * 1024 * 2 * 4;        // 16 KB
    float*  G   = (float*)ws;    ws += (size_t)32 * 50 * 50 * 4;        // 320 KB
    float*  qs  = (float*)ws;    ws += (size_t)32 * 52 * 4;             // 6.7 KB
    float*  cvs = (float*)ws;                                           // 77 KB

    hipLaunchKernelGGL(pack_whh, dim3(1024), dim3(256), 0, stream, Whh, WhhP);
    hipLaunchKernelGGL(pack_wr8, dim3(256), dim3(256), 0, stream, Wr, WrP);
    hipLaunchKernelGGL(prep_proj, dim3(2 * 32 * 7), dim3(256), 0, stream,
                       qv, Wq, bq, whp, QL, 7);
    hipLaunchKernelGGL(prep_proj, dim3(2 * 32 * 38), dim3(256), 0, stream,
                       cv, Wp, bp, hpp, PL, 38);
    hipLaunchKernelGGL(p1_prep, dim3(2 * 32 * 38), dim3(256), 0, stream,
                       cv, Wih, ln_g, P1);
    hipLaunchKernelGGL(vp_prep, dim3(512), dim3(256), 0, stream, qv, Wih, ln_g, VP);
    hipLaunchKernelGGL(gram_prep, dim3(32), dim3(256), 0, stream, qv, G, qs);
    hipLaunchKernelGGL(cvstats_prep, dim3(9600), dim3(256), 0, stream, cv, cvs);
    hipLaunchKernelGGL(c1c2_prep, dim3(8), dim3(256), 0, stream,
                       Wih, ln_g, ln_b, b_ih, b_hh, C12);
    hipLaunchKernelGGL(scan12, dim3(64), dim3(256), 0, stream,
                       cmask, qmask, Wg, bg, br, WhhP, WrP, whp, hpp, P1, VP, C12, G, qs, cvs,
                       out);
}

// Round 13
// 4141.860 us; speedup vs baseline: 1.1223x; 1.1202x over previous
//
#include <hip/hip_runtime.h>
#include <hip/hip_fp16.h>

typedef unsigned int u32;
typedef unsigned long long u64;
typedef _Float16 half2_t __attribute__((ext_vector_type(2)));

static constexpr int PL = 300;
static constexpr int QL = 50;
static constexpr int B  = 32;
static constexpr int D  = 256;
static constexpr int H  = 256;

__device__ __forceinline__ float fdot2(u32 w, u32 x, float acc) {
    return __builtin_amdgcn_fdot2(__builtin_bit_cast(half2_t, w),
                                  __builtin_bit_cast(half2_t, x), acc, false);
}
__device__ __forceinline__ u32 packh2(float a, float b) {
    half2_t h2; h2[0] = (_Float16)a; h2[1] = (_Float16)b;
    return __builtin_bit_cast(u32, h2);
}

// ---- pack Whh chunk8: dst[((dd*32+kc)*1024 + R)*4 + w] = cols kc*8+2w,+1 of row R ----
__global__ __launch_bounds__(256) void pack_whh(const float* __restrict__ Whh,
                                                u32* __restrict__ dst) {
    int id = blockIdx.x * 256 + threadIdx.x;    // < 262144
    int dd = id >> 17;
    int r  = id & 131071;
    int kc = r >> 12;
    int R  = (r >> 2) & 1023;
    int w  = r & 3;
    int k  = kc * 8 + w * 2;
    const float* s = &Whh[((size_t)dd * 1024 + R) * 256 + k];
    dst[id] = packh2(s[0], s[1]);
}

// ---- pack Wr chunk8: dst[((g*32+kc)*256 + c)*4 + w] ----
__global__ __launch_bounds__(256) void pack_wr8(const float* __restrict__ W,
                                                u32* __restrict__ dst) {
    int id = blockIdx.x * 256 + threadIdx.x;    // < 65536
    int g  = id >> 15;
    int r  = id & 32767;
    int kc = r >> 10;
    int c  = (r >> 2) & 255;
    int w  = r & 3;
    int k  = kc * 8 + w * 2;
    const float* s = &W[(g * 256 + c) * 256 + k];
    dst[id] = packh2(s[0], s[1]);
}

// ---- prep: out[g][b][t][h] = bias[g][h] + sum_d X[t][b][d]*W[g][h][d] ----
__global__ __launch_bounds__(256) void prep_proj(const float* __restrict__ X,
                                                 const float* __restrict__ W,
                                                 const float* __restrict__ Bv,
                                                 __half* __restrict__ out,
                                                 int T, int nt) {
    int id = blockIdx.x;
    int tb = id % nt; id /= nt;
    int b  = id % B;  id /= B;
    int g  = id;
    int t0 = tb * 8;
    int nr = T - t0; if (nr > 8) nr = 8;
    __shared__ __align__(16) float xs[8][256];
    int tid = threadIdx.x;
    for (int r = 0; r < nr; r++) xs[r][tid] = X[((t0 + r) * B + b) * D + tid];
    __syncthreads();
    const float4* wrow = (const float4*)&W[(g * H + tid) * D];
    float bb = Bv[g * H + tid];
    float acc[8];
#pragma unroll
    for (int r = 0; r < 8; r++) acc[r] = bb;
    for (int d4 = 0; d4 < D / 4; d4++) {
        float4 w = wrow[d4];
#pragma unroll
        for (int r = 0; r < 8; r++) {
            float4 x = *(const float4*)&xs[r][d4 * 4];
            acc[r] = fmaf(w.x, x.x, fmaf(w.y, x.y, fmaf(w.z, x.z, fmaf(w.w, x.w, acc[r]))));
        }
    }
    for (int r = 0; r < nr; r++)
        out[((g * B + b) * T + t0 + r) * H + tid] = __float2half(acc[r]);
}

// ---- P1[dd][b][t][1024] f16 = sum_{k<256} Wih[dd][R][k]*lng[dd][k]*cv[t][b][k] ----
__global__ __launch_bounds__(256) void p1_prep(const float* __restrict__ cv,
                                               const float* __restrict__ Wih,
                                               const float* __restrict__ lng,
                                               __half* __restrict__ P1) {
    int id = blockIdx.x;           // 2*32*38
    int tb = id % 38; id /= 38;
    int b  = id % 32; id /= 32;
    int dd = id;
    int t0 = tb * 8;
    int nr = PL - t0; if (nr > 8) nr = 8;
    __shared__ __align__(16) float xs[8][256];
    int tid = threadIdx.x;
    float g = lng[dd * 512 + tid];
    for (int r = 0; r < nr; r++)
        xs[r][tid] = cv[((size_t)(t0 + r) * B + b) * D + tid] * g;
    __syncthreads();
    for (int gc = 0; gc < 4; gc++) {
        int R = gc * 256 + tid;
        const float4* wrow = (const float4*)&Wih[((size_t)dd * 1024 + R) * 512];
        float acc[8] = {};
        for (int d4 = 0; d4 < 64; d4++) {
            float4 w = wrow[d4];
#pragma unroll
            for (int r = 0; r < 8; r++) {
                float4 x = *(const float4*)&xs[r][d4 * 4];
                acc[r] = fmaf(w.x, x.x, fmaf(w.y, x.y, fmaf(w.z, x.z, fmaf(w.w, x.w, acc[r]))));
            }
        }
        for (int r = 0; r < nr; r++)
            P1[((size_t)(dd * 32 + b) * PL + t0 + r) * 1024 + R] = __float2half(acc[r]);
    }
}

// ---- VP[dd][b][r][56 q] f16 = sum_k Wih[dd][r][256+k]*lng[dd][256+k]*qv[q][b][k] ----
__global__ __launch_bounds__(256) void vp_prep(const float* __restrict__ qv,
                                               const float* __restrict__ Wih,
                                               const float* __restrict__ lng,
                                               __half* __restrict__ VP) {
    int blk = blockIdx.x;               // 512
    int dd = blk >> 8, b = (blk >> 3) & 31, rc = blk & 7;
    __shared__ __align__(16) u32 qg[50 * 128];
    __shared__ __align__(16) u32 wch[128 * 128];
    int tid = threadIdx.x;
    for (int v = tid; v < 6400; v += 256) {
        int q = v >> 7, i = v & 127;
        float a = qv[((size_t)q * 32 + b) * 256 + 2 * i]     * lng[dd * 512 + 256 + 2 * i];
        float c = qv[((size_t)q * 32 + b) * 256 + 2 * i + 1] * lng[dd * 512 + 256 + 2 * i + 1];
        qg[v] = packh2(a, c);
    }
    for (int v = tid; v < 16384; v += 256) {
        int rl = v >> 7, i = v & 127;
        int r = rc * 128 + rl;
        float a = Wih[((size_t)dd * 1024 + r) * 512 + 256 + 2 * i];
        float c = Wih[((size_t)dd * 1024 + r) * 512 + 256 + 2 * i + 1];
        wch[v] = packh2(a, c);
    }
    __syncthreads();
    for (int p = tid; p < 128 * 56; p += 256) {
        int rl = p / 56, q = p % 56;
        int r = rc * 128 + rl;
        float acc = 0.f;
        if (q < 50) {
            const u32* qr = qg + q * 128;
            const u32* wr = wch + rl * 128;
#pragma unroll 8
            for (int i = 0; i < 128; i++) acc = fdot2(wr[i], qr[i], acc);
        }
        VP[((size_t)(dd * 32 + b) * 1024 + r) * 56 + q] = __float2half(acc);
    }
}

// ---- Gram G[b][50][50], rowsums qs[b][52] ----
__global__ __launch_bounds__(256) void gram_prep(const float* __restrict__ qv,
                                                 float* __restrict__ G,
                                                 float* __restrict__ qs) {
    int b = blockIdx.x;
    __shared__ float qvs[50 * 256];
    int tid = threadIdx.x;
    for (int v = tid; v < 12800; v += 256) {
        int q = v >> 8, k = v & 255;
        qvs[v] = qv[((size_t)q * 32 + b) * 256 + k];
    }
    __syncthreads();
    for (int p = tid; p < 2500; p += 256) {
        int q = p / 50, q2 = p % 50;
        float acc = 0.f;
        for (int k = 0; k < 256; k++) acc = fmaf(qvs[q * 256 + k], qvs[q2 * 256 + k], acc);
        G[((size_t)b * 50 + q) * 50 + q2] = acc;
    }
    if (tid < 52) {
        float s = 0.f;
        if (tid < 50) for (int k = 0; k < 256; k++) s += qvs[tid * 256 + k];
        qs[b * 52 + tid] = s;
    }
}

// ---- cvstats[b][t][2] = {sum, sumsq} over cv[t,b,:] ----
__global__ __launch_bounds__(256) void cvstats_prep(const float* __restrict__ cv,
                                                    float* __restrict__ st) {
    int blk = blockIdx.x;               // 9600
    int t = blk >> 5, b = blk & 31;
    int tid = threadIdx.x;
    float v = cv[((size_t)t * 32 + b) * 256 + tid];
    float s = v, s2 = v * v;
#pragma unroll
    for (int m = 32; m; m >>= 1) { s += __shfl_xor(s, m, 64); s2 += __shfl_xor(s2, m, 64); }
    __shared__ float red[8];
    if ((tid & 63) == 0) { red[(tid >> 6) * 2] = s; red[(tid >> 6) * 2 + 1] = s2; }
    __syncthreads();
    if (tid == 0) {
        float S = red[0] + red[2] + red[4] + red[6];
        float S2 = red[1] + red[3] + red[5] + red[7];
        st[((size_t)b * 300 + t) * 2] = S;
        st[((size_t)b * 300 + t) * 2 + 1] = S2;
    }
}

// ---- C12[dd][R][2] = {sum_k W[R,k]*gamma[k], sum_k W[R,k]*beta[k] + bih + bhh} ----
__global__ __launch_bounds__(256) void c1c2_prep(const float* __restrict__ Wih,
                                                 const float* __restrict__ lng,
                                                 const float* __restrict__ lnb,
                                                 const float* __restrict__ bih,
                                                 const float* __restrict__ bhh,
                                                 float* __restrict__ C12) {
    int id = blockIdx.x * 256 + threadIdx.x;    // < 2048
    int dd = id >> 10, R = id & 1023;
    float s1 = 0.f, s2 = 0.f;
    const float* wr = &Wih[((size_t)dd * 1024 + R) * 512];
    for (int k = 0; k < 512; k++) {
        float w = wr[k];
        s1 = fmaf(w, lng[dd * 512 + k], s1);
        s2 = fmaf(w, lnb[dd * 512 + k], s2);
    }
    C12[(size_t)id * 2] = s1;
    C12[(size_t)id * 2 + 1] = s2 + bih[dd * 1024 + R] + bhh[dd * 1024 + R];
}

// ================= main scan: 64 independent blocks x 1024 threads (4 waves/SIMD) =================
// Thread tid owns gate row tid (1 uint4/kc); threads <256 also own Wr row tid (hr).
__global__ __launch_bounds__(1024, 1) void scan13(
    const int*   __restrict__ cmask,    // [32][300]
    const int*   __restrict__ qmask,    // [32][50]
    const float* __restrict__ Wgv,      // [2][256]
    const float* __restrict__ bgv,      // [2]
    const float* __restrict__ brp,      // [2][256]
    const u32*   __restrict__ WhhP,     // [2][32 kc][1024][4] chunk8
    const u32*   __restrict__ WrP,      // [2][32 kc][256][4] chunk8
    const __half* __restrict__ whp,     // [2][32][50][256]
    const __half* __restrict__ hpp,     // [2][32][300][256]
    const __half* __restrict__ P1,      // [2*32][300][1024]
    const __half* __restrict__ VP,      // [2*32][1024][56]
    const float* __restrict__ C12,      // [2][1024][2]
    const float* __restrict__ G,        // [32][50][50]
    const float* __restrict__ qsr,      // [32][52]
    const float* __restrict__ cvst,     // [32][300][2]
    float* __restrict__ out)            // [300][32][512]
{
    int blk = blockIdx.x;
    int dd = blk >> 5, j = blk & 31;
    int tid = threadIdx.x;              // 0..1023
    int lane = tid & 63, wave = tid >> 6;

    __shared__ __align__(16) u32 sh_wh[6400];   // wh f16 [50][256]
    __shared__ float sh_G[50 * 50];
    __shared__ __align__(16) u32 sh_h[128];     // own h(t) f16 pairs
    __shared__ float sh_a[256];
    __shared__ float sh_gk[1024];
    __shared__ float sh_af[64];
    __shared__ __align__(16) u32 sh_al2[28];
    __shared__ float sh_alpha[64];
    __shared__ float sh_qb[64];
    __shared__ float sh_qs[52];
    __shared__ float sh_r2[4];
    __shared__ float sh_cs[2];
    __shared__ int   sh_len1;

    // ---------- one-time staging ----------
    {
        const u32* whsrc = (const u32*)(whp + (size_t)(dd * 32 + j) * QL * H);
        for (int i = tid; i < 6400; i += 1024) sh_wh[i] = whsrc[i];
    }
    for (int v = tid; v < 2500; v += 1024) sh_G[v] = G[(size_t)j * 2500 + v];
    if (tid < 52) sh_qs[tid] = qsr[j * 52 + tid];
    if (tid >= 64 && tid < 128) {
        int q = tid - 64;
        sh_qb[q] = (q < QL) ? (qmask[j * QL + q] ? 0.f : -1e30f) : -1e30f;
    }
    if (tid >= 128 && tid < 256) sh_h[tid - 128] = 0;
    if (tid == 0) sh_len1 = 0;
    __syncthreads();
    {
        int s = 0;
        for (int tt = tid; tt < PL; tt += 1024) s += cmask[j * PL + tt];
#pragma unroll
        for (int m = 32; m; m >>= 1) s += __shfl_xor(s, m, 64);
        if (lane == 0) atomicAdd(&sh_len1, s);
    }
    __syncthreads();
    int len_j = sh_len1;

    float wgr[4];
#pragma unroll
    for (int i = 0; i < 4; i++) wgr[i] = Wgv[dd * H + lane + 64 * i];
    float bgs = bgv[dd];
    float brv = (tid < 256) ? brp[dd * H + tid] : 0.f;
    float C1r = C12[((size_t)dd * 1024 + tid) * 2];
    float C2r = C12[((size_t)dd * 1024 + tid) * 2 + 1];
    float c_reg = 0.f;

    // zero own-batch masked tail
    if (tid < 256)
        for (int t = len_j; t < PL; t++)
            out[((size_t)t * B + j) * 512 + dd * 256 + tid] = 0.f;

    const __half* hpb = hpp + (size_t)(dd * 32 + j) * PL * H;
    const u32* VPu = (const u32*)VP;
    const uint4* whq = (const uint4*)WhhP + (size_t)dd * 32 * 1024;  // [kc*1024 + R]
    const uint4* wrq = (const uint4*)WrP  + (size_t)dd * 32 * 256;   // [kc*256 + c]
    bool ishr = (tid < 256);

    for (int t = 0; t < len_j; t++) {
        int tsj = dd ? (len_j - 1 - t) : t;
        __syncthreads();   // sh_h / sh_gk stable

        // ---- A: own-row cached loads + VP prefetch ----
        float p1v = __half2float(P1[((size_t)(dd * 32 + j) * PL + tsj) * 1024 + tid]);
        float hpv = ishr ? __half2float(hpb[(size_t)tsj * H + tid]) : 0.f;
        if (tid == 0) {
            sh_cs[0] = cvst[((size_t)j * 300 + tsj) * 2];
            sh_cs[1] = cvst[((size_t)j * 300 + tsj) * 2 + 1];
        }
        uint4 vp[7];
        {
            const uint4* vr = (const uint4*)(VPu + ((size_t)(dd * 32 + j) * 1024 + tid) * 28);
#pragma unroll
            for (int i = 0; i < 7; i++) vp[i] = vr[i];
        }

        // ---- B: L2-streamed GEMV: 1 gate row; threads<256 also 1 Wr row ----
        float g0 = 0.f, hr = 0.f;
#pragma unroll 8
        for (int kc = 0; kc < 32; kc++) {
            uint4 hx = *(const uint4*)(sh_h + kc * 4);          // LDS broadcast
            uint4 wa = whq[kc * 1024 + tid];
            g0 = fdot2(wa.x, hx.x, g0); g0 = fdot2(wa.y, hx.y, g0);
            g0 = fdot2(wa.z, hx.z, g0); g0 = fdot2(wa.w, hx.w, g0);
            if (ishr) {
                uint4 wr = wrq[kc * 256 + tid];
                hr = fdot2(wr.x, hx.x, hr); hr = fdot2(wr.y, hx.y, hr);
                hr = fdot2(wr.z, hx.z, hr); hr = fdot2(wr.w, hx.w, hr);
            }
        }
        if (ishr) sh_a[tid] = hr + brv + hpv;
        __syncthreads();

        // ---- G: attention logits (16 waves, q strided) ----
        {
            float av[4];
#pragma unroll
            for (int i = 0; i < 4; i++) av[i] = sh_a[lane + 64 * i];
            const __half* wh16 = (const __half*)sh_wh;
            for (int q = wave; q < QL; q += 16) {
                float a = 0.f;
#pragma unroll
                for (int i = 0; i < 4; i++) {
                    float xx = (float)wh16[q * 256 + lane + 64 * i] + av[i];
                    float e = __expf(2.f * xx);
                    a = fmaf(wgr[i], (e - 1.f) / (e + 1.f), a);
                }
#pragma unroll
                for (int m = 32; m; m >>= 1) a += __shfl_xor(a, m, 64);
                if (lane == 0) sh_alpha[q] = a + bgs + sh_qb[q];
            }
        }
        __syncthreads();

        // ---- H: softmax (wave 0) ----
        if (wave == 0) {
            float v = (lane < QL) ? sh_alpha[lane] : -1e30f;
            float m = v;
#pragma unroll
            for (int s = 32; s; s >>= 1) m = fmaxf(m, __shfl_xor(m, s, 64));
            float e = (lane < QL) ? __expf(v - m) : 0.f;
            float sum = e;
#pragma unroll
            for (int s = 32; s; s >>= 1) sum += __shfl_xor(sum, s, 64);
            float al = (lane < QL) ? e / sum : 0.f;
            sh_af[lane] = al;
            float alo = __shfl_xor(al, 1, 64);
            if (!(lane & 1) && lane < 56) sh_al2[lane >> 1] = packh2(al, alo);
        }
        __syncthreads();

        // ---- I: LN stats from Gram ----
        if (wave == 0) {
            float gd = 0.f;
            if (lane < QL) {
                const float* Grow = sh_G + lane * 50;
                float aq = sh_af[lane];
                for (int q2 = 0; q2 < QL; q2++) gd = fmaf(Grow[q2], sh_af[q2], gd);
                gd *= aq;
            }
#pragma unroll
            for (int m = 32; m; m >>= 1) gd += __shfl_xor(gd, m, 64);
            if (lane == 0) sh_r2[0] = gd;
        } else if (wave == 1) {
            float s = (lane < QL) ? sh_af[lane] * sh_qs[lane] : 0.f;
#pragma unroll
            for (int m = 32; m; m >>= 1) s += __shfl_xor(s, m, 64);
            if (lane == 0) sh_r2[1] = s;
        }
        __syncthreads();

        // ---- J+K1: alpha.VP + gate assembly -> sh_gk ----
        {
            float acc = 0.f;
#pragma unroll
            for (int i = 0; i < 7; i++) {
                acc = fdot2(vp[i].x, sh_al2[i * 4 + 0], acc);
                acc = fdot2(vp[i].y, sh_al2[i * 4 + 1], acc);
                acc = fdot2(vp[i].z, sh_al2[i * 4 + 2], acc);
                acc = fdot2(vp[i].w, sh_al2[i * 4 + 3], acc);
            }
            float mu = (sh_cs[0] + sh_r2[1]) * (1.f / 512.f);
            float E2 = (sh_cs[1] + sh_r2[0]) * (1.f / 512.f);
            float rs = rsqrtf(E2 - mu * mu + 1e-5f);
            sh_gk[tid] = g0 + rs * (p1v + acc) - rs * mu * C1r + C2r;
        }
        __syncthreads();

        // ---- K2: LSTM pointwise (tid<256) + h(t+1) to LDS + out ----
        if (ishr) {
            float gi = sh_gk[tid], gf = sh_gk[256 + tid];
            float gg = sh_gk[512 + tid], go = sh_gk[768 + tid];
            float si = 1.f / (1.f + __expf(-gi));
            float sf = 1.f / (1.f + __expf(-gf));
            float so = 1.f / (1.f + __expf(-go));
            float eg = __expf(2.f * gg); float tg = (eg - 1.f) / (eg + 1.f);
            float c = sf * c_reg + si * tg;
            float ec = __expf(2.f * c); float tc = (ec - 1.f) / (ec + 1.f);
            float hv = so * tc;
            c_reg = c;
            float ho = __shfl_xor(hv, 1, 64);
            if (!(tid & 1)) sh_h[tid >> 1] = packh2(hv, ho);
            out[((size_t)tsj * B + j) * 512 + dd * 256 + tid] = hv;
        }
    }
}

extern "C" void kernel_launch(void* const* d_in, const int* in_sizes, int n_in,
                              void* d_out, int out_size, void* d_ws, size_t ws_size,
                              hipStream_t stream) {
    const float* cv    = (const float*)d_in[0];
    const int*   cmask = (const int*)  d_in[1];
    const float* qv    = (const float*)d_in[2];
    const int*   qmask = (const int*)  d_in[3];
    const float* Wq    = (const float*)d_in[4];
    const float* bq    = (const float*)d_in[5];
    const float* Wp    = (const float*)d_in[6];
    const float* bp    = (const float*)d_in[7];
    const float* Wr    = (const float*)d_in[8];
    const float* br    = (const float*)d_in[9];
    const float* Wg    = (const float*)d_in[10];
    const float* bg    = (const float*)d_in[11];
    const float* ln_g  = (const float*)d_in[12];
    const float* ln_b  = (const float*)d_in[13];
    const float* Wih   = (const float*)d_in[14];
    const float* Whh   = (const float*)d_in[15];
    const float* b_ih  = (const float*)d_in[16];
    const float* b_hh  = (const float*)d_in[17];
    float* out = (float*)d_out;

    uint8_t* ws = (uint8_t*)d_ws;
    u32*    WhhP = (u32*)ws;     ws += (size_t)2 * 32 * 1024 * 4 * 4;   // 1.05 MB
    u32*    WrP  = (u32*)ws;     ws += (size_t)2 * 32 * 256 * 4 * 4;    // 256 KB
    __half* VP  = (__half*)ws;   ws += (size_t)2 * 32 * 1024 * 56 * 2;  // 7.34 MB
    __half* whp = (__half*)ws;   ws += (size_t)2 * 32 * 50 * 256 * 2;   // 1.64 MB
    __half* hpp = (__half*)ws;   ws += (size_t)2 * 32 * 300 * 256 * 2;  // 9.83 MB
    __half* P1  = (__half*)ws;   ws += (size_t)2 * 32 * 300 * 1024 * 2; // 39.32 MB
    float*  C12 = (float*)ws;    ws += (size_t)2 * 1024 * 2 * 4;        // 16 KB
    float*  G   = (float*)ws;    ws += (size_t)32 * 50 * 50 * 4;        // 320 KB
    float*  qs  = (float*)ws;    ws += (size_t)32 * 52 * 4;             // 6.7 KB
    float*  cvs = (float*)ws;                                           // 77 KB

    hipLaunchKernelGGL(pack_whh, dim3(1024), dim3(256), 0, stream, Whh, WhhP);
    hipLaunchKernelGGL(pack_wr8, dim3(256), dim3(256), 0, stream, Wr, WrP);
    hipLaunchKernelGGL(prep_proj, dim3(2 * 32 * 7), dim3(256), 0, stream,
                       qv, Wq, bq, whp, QL, 7);
    hipLaunchKernelGGL(prep_proj, dim3(2 * 32 * 38), dim3(256), 0, stream,
                       cv, Wp, bp, hpp, PL, 38);
    hipLaunchKernelGGL(p1_prep, dim3(2 * 32 * 38), dim3(256), 0, stream,
                       cv, Wih, ln_g, P1);
    hipLaunchKernelGGL(vp_prep, dim3(512), dim3(256), 0, stream, qv, Wih, ln_g, VP);
    hipLaunchKernelGGL(gram_prep, dim3(32), dim3(256), 0, stream, qv, G, qs);
    hipLaunchKernelGGL(cvstats_prep, dim3(9600), dim3(256), 0, stream, cv, cvs);
    hipLaunchKernelGGL(c1c2_prep, dim3(8), dim3(256), 0, stream,
                       Wih, ln_g, ln_b, b_ih, b_hh, C12);
    hipLaunchKernelGGL(scan13, dim3(64), dim3(1024), 0, stream,
                       cmask, qmask, Wg, bg, br, WhhP, WrP, whp, hpp, P1, VP, C12, G, qs, cvs,
                       out);
}